// Round 1
// 409.127 us; speedup vs baseline: 1.3317x; 1.3317x over previous
//
#include <hip/hip_runtime.h>

// ShiftWindowMSA (Swin) fused kernels for MI355X (gfx950).
// B=16, H=W=64, C=512, NH=16, hd=32, WS=8, SS=4 -> 1024 windows x 64 tokens.
// FP32 inputs/outputs. Weights bf16 in d_ws; fp32 accumulation.
//
// R1: baseline was occupancy-bound (LDS 125952 B -> 1 block/CU -> 1 wave/SIMD;
// MfmaUtil 10%, VALUBusy 20%, HBM 7%). The shifted-window input is now
// pre-staged to workspace as bf16 in an MFMA-tiled layout [win][k/32][tok][32]
// by cvt_all, so k_fused LDS drops to 66560 B -> 2 blocks/CU -> 2 waves/SIMD.
// All per-wave-private barriers in the head loop are removed (intra-wave
// lgkmcnt ordering is compiler-inserted; scratch is wave-private).
// Falls back to the old in-kernel-staging path if ws_size < 66 MiB.

typedef short  short8  __attribute__((ext_vector_type(8)));
typedef short  short4v __attribute__((ext_vector_type(4)));
typedef float  floatx4 __attribute__((ext_vector_type(4)));

#define DEVI static __device__ __forceinline__

DEVI unsigned short f2bf(float f) {
    union { float f; unsigned int u; } v;
    v.f = f;
    return (unsigned short)((v.u + 0x7fffu + ((v.u >> 16) & 1u)) >> 16);
}

// ---------------------------------------------------------------------------
// cvt_all: blocks [0,1024) convert qkv_w (1536x512) then proj_w (512x512)
// fp32 -> bf16 into wbf. Blocks [1024, 17408) gather the cyclic-shifted
// windows of query into xw as bf16, tiled [win][kc=k/32][tok 64][32] so the
// fused kernel's A-fragment loads are contiguous 1 KiB/wave.
// ---------------------------------------------------------------------------
__global__ void cvt_all(const float* __restrict__ query,
                        const float* __restrict__ qkv_w,
                        const float* __restrict__ proj_w,
                        unsigned short* __restrict__ wbf,
                        unsigned short* __restrict__ xw) {
    const int bid = blockIdx.x;
    if (bid < 1024) {
        const int idx = ((bid << 8) + threadIdx.x) << 2;
        const float* src = (idx < 786432) ? (qkv_w + idx) : (proj_w + (idx - 786432));
        const floatx4 v = *(const floatx4*)src;
        short4v o;
        o[0] = (short)f2bf(v[0]); o[1] = (short)f2bf(v[1]);
        o[2] = (short)f2bf(v[2]); o[3] = (short)f2bf(v[3]);
        *(short4v*)(wbf + idx) = o;
        return;
    }
    const int c   = ((bid - 1024) << 8) + threadIdx.x;   // 0 .. 4194303
    const int win = c >> 12;
    const int rem = c & 4095;
    const int jc  = rem & 3;                             // 8-short chunk in 32
    const int tok = (rem >> 2) & 63;
    const int kc  = rem >> 8;                            // 0..15 (k/32)
    const int b   = win >> 6, wy = (win >> 3) & 7, wx = win & 7;
    const int ty  = tok >> 3, tx = tok & 7;
    const int gh  = ((wy << 3) + ty + 4) & 63;
    const int gw  = ((wx << 3) + tx + 4) & 63;
    const float* src = query + (((b << 12) + (gh << 6) + gw) << 9) + (kc << 5) + (jc << 3);
    const floatx4 v0 = *(const floatx4*)src;
    const floatx4 v1 = *(const floatx4*)(src + 4);
    short8 s;
    s[0] = (short)f2bf(v0[0]); s[1] = (short)f2bf(v0[1]);
    s[2] = (short)f2bf(v0[2]); s[3] = (short)f2bf(v0[3]);
    s[4] = (short)f2bf(v1[0]); s[5] = (short)f2bf(v1[1]);
    s[6] = (short)f2bf(v1[2]); s[7] = (short)f2bf(v1[3]);
    *(short8*)(xw + (win << 15) + (kc << 11) + (tok << 5) + (jc << 3)) = s;
}

// ---------------------------------------------------------------------------
// Fused kernel: one block (4 waves) per window, 4 heads per wave.
// GX=1: A-operands for QKV read from pre-tiled xw (global/L2); LDS = 66560 B
//       (per-wave scratch in phase 1, attn-out [64][520] overlay in phase 2).
// GX=0: legacy path, stages x into LDS (125952 B).
// MFMA 16x16x32 bf16 layouts:
//   A[m=lane&15][k=quad*8+j], B[n=lane&15][k=quad*8+j], D: row=quad*4+reg, col=lane&15.
// ---------------------------------------------------------------------------
template<int GX>
__global__ __launch_bounds__(256, GX ? 2 : 1)
void k_fused(const float* __restrict__ query,
             const unsigned short* __restrict__ wbf,
             const unsigned short* __restrict__ xw,
             const float* __restrict__ qkv_b,
             const float* __restrict__ proj_b,
             const float* __restrict__ bias_table,
             float* __restrict__ out)
{
    // GX: phase1 = 4 waves x 7424 shorts scratch (29696), phase2 = [64][520] (33280).
    // legacy: xs 64x520 (33280) + 4 x 7424 = 62976 shorts.
    __shared__ __align__(16) unsigned short smem[GX ? 33280 : 62976];

    const int tid  = threadIdx.x;
    const int lane = tid & 63;
    const int l15  = lane & 15;
    const int quad = lane >> 4;
    const int wave = tid >> 6;

    const int win = blockIdx.x;
    const int b   = win >> 6;
    const int wy  = (win >> 3) & 7;
    const int wx  = win & 7;
    const int mid = ((wy == 7) ? 2 : 0) | ((wx == 7) ? 1 : 0);

    unsigned short* xs  = smem;                          // [64][520] (phase 2; legacy also phase 1)
    unsigned short* wb  = smem + (GX ? 0 : 33280) + wave * 7424;
    unsigned short* qbf = wb;                            // [64][40]
    unsigned short* kbf = wb + 2560;                     // [64][40]
    unsigned short* vT  = wb + 5120;                     // [32][72]
    unsigned short* pbf = wb;                            // [64][72], overlays q+k

    if constexpr (!GX) {
        // ---- stage shifted window (fp32 -> bf16), roll folded into the gather ----
        #pragma unroll
        for (int it = 0; it < 32; ++it) {
            const int c   = tid + (it << 8);
            const int tok = c >> 7;
            const int fo  = (c & 127) << 2;
            const int ty  = tok >> 3, tx = tok & 7;
            const int gh  = ((wy << 3) + ty + 4) & 63;
            const int gw  = ((wx << 3) + tx + 4) & 63;
            const floatx4 v = *(const floatx4*)(query + (((b << 12) + (gh << 6) + gw) << 9) + fo);
            short4v s;
            s[0] = (short)f2bf(v[0]); s[1] = (short)f2bf(v[1]);
            s[2] = (short)f2bf(v[2]); s[3] = (short)f2bf(v[3]);
            *(short4v*)&xs[tok * 520 + fo] = s;
        }
        __syncthreads();
    }

    // Pre-tiled A base: xw[win][kk/32][tok][32] -> addr = win*32768 + kk*64 + tok*32 + q*8
    const unsigned short* xa = xw + (win << 15) + (l15 << 5) + (quad << 3);

    const float scale = 0.17677669529663687f;            // 1/sqrt(32)
    const floatx4 fz = {0.f, 0.f, 0.f, 0.f};

    unsigned int po[4][16];                              // per-head packed bf16 outputs

    for (int hh = 0; hh < 4; ++hh) {
        const int h = (wave << 2) + hh;

        // ---------------- QKV projection for this head ----------------
        floatx4 accq[4][2], acck[4][2], accv[4][2];
        #pragma unroll
        for (int mt = 0; mt < 4; ++mt)
            #pragma unroll
            for (int nt = 0; nt < 2; ++nt) { accq[mt][nt] = fz; acck[mt][nt] = fz; accv[mt][nt] = fz; }

        const unsigned short* wq = wbf + ((h << 5) + l15) * 512 + (quad << 3);
        const unsigned short* wk = wq + 512 * 512;
        const unsigned short* wv = wk + 512 * 512;

        #pragma unroll 2
        for (int kk = 0; kk < 512; kk += 32) {
            short8 a[4], bq[2], bk2[2], bv2[2];
            #pragma unroll
            for (int mt = 0; mt < 4; ++mt) {
                if constexpr (GX)
                    a[mt] = *(const short8*)(xa + (kk << 6) + (mt << 9));
                else
                    a[mt] = *(const short8*)&xs[((mt << 4) + l15) * 520 + kk + (quad << 3)];
            }
            #pragma unroll
            for (int nt = 0; nt < 2; ++nt) {
                const int ro = (nt << 4) * 512 + kk;
                bq[nt]  = *(const short8*)(wq + ro);
                bk2[nt] = *(const short8*)(wk + ro);
                bv2[nt] = *(const short8*)(wv + ro);
            }
            #pragma unroll
            for (int nt = 0; nt < 2; ++nt)
                #pragma unroll
                for (int mt = 0; mt < 4; ++mt) {
                    accq[mt][nt] = __builtin_amdgcn_mfma_f32_16x16x32_bf16(a[mt], bq[nt],  accq[mt][nt], 0, 0, 0);
                    acck[mt][nt] = __builtin_amdgcn_mfma_f32_16x16x32_bf16(a[mt], bk2[nt], acck[mt][nt], 0, 0, 0);
                    accv[mt][nt] = __builtin_amdgcn_mfma_f32_16x16x32_bf16(a[mt], bv2[nt], accv[mt][nt], 0, 0, 0);
                }
        }

        // bias add; q,k row-major [tok][hd], v transposed [hd][tok] into LDS
        #pragma unroll
        for (int nt = 0; nt < 2; ++nt) {
            const int cix = (h << 5) + (nt << 4) + l15;
            const float bq_ = qkv_b[cix];
            const float bk_ = qkv_b[512 + cix];
            const float bv_ = qkv_b[1024 + cix];
            #pragma unroll
            for (int mt = 0; mt < 4; ++mt) {
                short4v vv;
                #pragma unroll
                for (int r = 0; r < 4; ++r) {
                    const int row = (mt << 4) + (quad << 2) + r;
                    qbf[row * 40 + (nt << 4) + l15] = f2bf(accq[mt][nt][r] + bq_);
                    kbf[row * 40 + (nt << 4) + l15] = f2bf(acck[mt][nt][r] + bk_);
                    vv[r] = (short)f2bf(accv[mt][nt][r] + bv_);
                }
                *(short4v*)&vT[((nt << 4) + l15) * 72 + (mt << 4) + (quad << 2)] = vv;
            }
        }
        // (no barrier: qbf/kbf/vT are wave-private; lgkmcnt ordering suffices)

        // ---------------- Q K^T ----------------
        short8 qa[4], ka[4];
        #pragma unroll
        for (int t = 0; t < 4; ++t) {
            qa[t] = *(const short8*)&qbf[((t << 4) + l15) * 40 + (quad << 3)];
            ka[t] = *(const short8*)&kbf[((t << 4) + l15) * 40 + (quad << 3)];
        }
        floatx4 s4[4][4];
        #pragma unroll
        for (int mt = 0; mt < 4; ++mt)
            #pragma unroll
            for (int nt = 0; nt < 4; ++nt)
                s4[mt][nt] = __builtin_amdgcn_mfma_f32_16x16x32_bf16(qa[mt], ka[nt], fz, 0, 0, 0);

        // ------- logits: scale + rel-pos bias (closed-form idx) + shift mask ---
        int  gjv[4]; bool jrow[4], jcol[4];
        #pragma unroll
        for (int nt = 0; nt < 4; ++nt) {
            const int j  = (nt << 4) + l15;
            const int j2 = 63 - j;
            gjv[nt]  = 15 * (j2 >> 3) + (j2 & 7);
            jrow[nt] = (j >> 3) < 4;
            jcol[nt] = (j & 7) < 4;
        }
        #pragma unroll
        for (int mt = 0; mt < 4; ++mt) {
            const int i0  = (mt << 4) + (quad << 2);
            const int fi0 = 15 * (i0 >> 3) + (i0 & 7);
            const bool irow = (i0 >> 3) < 4;
            const bool icol = (i0 & 7) == 0;
            #pragma unroll
            for (int nt = 0; nt < 4; ++nt) {
                float mval = 0.0f;
                if ((mid & 2) && (irow != jrow[nt])) mval = -100.0f;
                if ((mid & 1) && (icol != jcol[nt])) mval = -100.0f;
                const float* bp = bias_table + (fi0 + gjv[nt]) * 16 + h;
                #pragma unroll
                for (int r = 0; r < 4; ++r)
                    s4[mt][nt][r] = s4[mt][nt][r] * scale + bp[r * 16] + mval;
            }
        }

        // ---- softmax (max-subtracted, NaN-proof) -> normalized P in LDS ------
        #pragma unroll
        for (int mt = 0; mt < 4; ++mt)
            #pragma unroll
            for (int r = 0; r < 4; ++r) {
                float m = fmaxf(fmaxf(s4[mt][0][r], s4[mt][1][r]),
                                fmaxf(s4[mt][2][r], s4[mt][3][r]));
                m = fmaxf(m, __shfl_xor(m, 1));
                m = fmaxf(m, __shfl_xor(m, 2));
                m = fmaxf(m, __shfl_xor(m, 4));
                m = fmaxf(m, __shfl_xor(m, 8));
                float loc = 0.0f;
                #pragma unroll
                for (int nt = 0; nt < 4; ++nt) {
                    s4[mt][nt][r] = __expf(s4[mt][nt][r] - m);
                    loc += s4[mt][nt][r];
                }
                loc += __shfl_xor(loc, 1);
                loc += __shfl_xor(loc, 2);
                loc += __shfl_xor(loc, 4);
                loc += __shfl_xor(loc, 8);
                const float inv = 1.0f / loc;            // loc >= 1 (max entry = 1)
                const int row = (mt << 4) + (quad << 2) + r;
                #pragma unroll
                for (int nt = 0; nt < 4; ++nt)
                    pbf[row * 72 + (nt << 4) + l15] = f2bf(s4[mt][nt][r] * inv);
            }
        // (no barrier: pbf is wave-private)

        // ---------------- P V ----------------
        short8 pa[4][2], va[2][2];
        #pragma unroll
        for (int mt = 0; mt < 4; ++mt)
            #pragma unroll
            for (int ks = 0; ks < 2; ++ks)
                pa[mt][ks] = *(const short8*)&pbf[((mt << 4) + l15) * 72 + (ks << 5) + (quad << 3)];
        #pragma unroll
        for (int nt = 0; nt < 2; ++nt)
            #pragma unroll
            for (int ks = 0; ks < 2; ++ks)
                va[nt][ks] = *(const short8*)&vT[((nt << 4) + l15) * 72 + (ks << 5) + (quad << 3)];

        #pragma unroll
        for (int mt = 0; mt < 4; ++mt)
            #pragma unroll
            for (int nt = 0; nt < 2; ++nt) {
                floatx4 acc = fz;
                acc = __builtin_amdgcn_mfma_f32_16x16x32_bf16(pa[mt][0], va[nt][0], acc, 0, 0, 0);
                acc = __builtin_amdgcn_mfma_f32_16x16x32_bf16(pa[mt][1], va[nt][1], acc, 0, 0, 0);
                const int pi = ((mt << 1) + nt) << 1;
                po[hh][pi]     = (unsigned int)f2bf(acc[0]) | ((unsigned int)f2bf(acc[1]) << 16);
                po[hh][pi + 1] = (unsigned int)f2bf(acc[2]) | ((unsigned int)f2bf(acc[3]) << 16);
            }
    }
    __syncthreads();   // all waves done with phase-1 LDS (scratch / xs)

    // ---- overlay attention output into xs: [tok][ch], ch = h*32 + nt*16 + l15 ----
    #pragma unroll
    for (int hh = 0; hh < 4; ++hh) {
        const int ch0 = (((wave << 2) + hh) << 5) + l15;
        #pragma unroll
        for (int mt = 0; mt < 4; ++mt)
            #pragma unroll
            for (int nt = 0; nt < 2; ++nt) {
                const int pi = ((mt << 1) + nt) << 1;
                #pragma unroll
                for (int r = 0; r < 4; ++r) {
                    const int row = (mt << 4) + (quad << 2) + r;
                    const unsigned int w = po[hh][pi + (r >> 1)];
                    xs[row * 520 + ch0 + (nt << 4)] =
                        (unsigned short)((w >> ((r & 1) << 4)) & 0xffffu);
                }
            }
    }
    __syncthreads();

    // ---------------- output projection + window-reverse + reverse roll --------
    const unsigned short* pwb = wbf + 786432;            // proj_w bf16
    for (int pass = 0; pass < 2; ++pass) {
        const int co0 = (wave << 7) + (pass << 6);
        floatx4 acc[4][4];
        #pragma unroll
        for (int mt = 0; mt < 4; ++mt)
            #pragma unroll
            for (int nt = 0; nt < 4; ++nt) acc[mt][nt] = fz;

        const unsigned short* wp = pwb + (co0 + l15) * 512 + (quad << 3);

        #pragma unroll 2
        for (int kk = 0; kk < 512; kk += 32) {
            short8 a[4], bfr[4];
            #pragma unroll
            for (int mt = 0; mt < 4; ++mt)
                a[mt] = *(const short8*)&xs[((mt << 4) + l15) * 520 + kk + (quad << 3)];
            #pragma unroll
            for (int nt = 0; nt < 4; ++nt)
                bfr[nt] = *(const short8*)(wp + (nt << 4) * 512 + kk);
            #pragma unroll
            for (int nt = 0; nt < 4; ++nt)
                #pragma unroll
                for (int mt = 0; mt < 4; ++mt)
                    acc[mt][nt] = __builtin_amdgcn_mfma_f32_16x16x32_bf16(a[mt], bfr[nt], acc[mt][nt], 0, 0, 0);
        }

        #pragma unroll
        for (int nt = 0; nt < 4; ++nt) {
            const float pb_ = proj_b[co0 + (nt << 4) + l15];
            #pragma unroll
            for (int mt = 0; mt < 4; ++mt)
                #pragma unroll
                for (int r = 0; r < 4; ++r) {
                    const int tok = (mt << 4) + (quad << 2) + r;
                    const int ty = tok >> 3, tx = tok & 7;
                    const int gh = ((wy << 3) + ty + 4) & 63;
                    const int gw = ((wx << 3) + tx + 4) & 63;
                    out[(((b << 12) + (gh << 6) + gw) << 9) + co0 + (nt << 4) + l15] =
                        acc[mt][nt][r] + pb_;
                }
        }
    }
}

// ---------------------------------------------------------------------------
extern "C" void kernel_launch(void* const* d_in, const int* in_sizes, int n_in,
                              void* d_out, int out_size, void* d_ws, size_t ws_size,
                              hipStream_t stream) {
    const float* query      = (const float*)d_in[0];
    const float* qkv_w      = (const float*)d_in[1];
    const float* qkv_b      = (const float*)d_in[2];
    const float* proj_w     = (const float*)d_in[3];
    const float* proj_b     = (const float*)d_in[4];
    const float* bias_table = (const float*)d_in[5];
    // d_in[6] = rel_index (closed-form, unused), d_in[7]=H, d_in[8]=W (constants)

    unsigned short* wbf = (unsigned short*)d_ws;         // 2 MiB bf16 weights
    unsigned short* xw  = wbf + 1048576;                 // 64 MiB bf16 tiled windows

    const size_t need = (size_t)(1048576 + 33554432) * sizeof(unsigned short);
    if (ws_size >= need) {
        hipLaunchKernelGGL(cvt_all, dim3(17408), dim3(256), 0, stream,
                           query, qkv_w, proj_w, wbf, xw);
        hipLaunchKernelGGL(HIP_KERNEL_NAME(k_fused<1>), dim3(1024), dim3(256), 0, stream,
                           query, wbf, xw, qkv_b, proj_b, bias_table, (float*)d_out);
    } else {
        hipLaunchKernelGGL(cvt_all, dim3(1024), dim3(256), 0, stream,
                           query, qkv_w, proj_w, wbf, wbf);
        hipLaunchKernelGGL(HIP_KERNEL_NAME(k_fused<0>), dim3(1024), dim3(256), 0, stream,
                           query, wbf, wbf, qkv_b, proj_b, bias_table, (float*)d_out);
    }
}